// Round 13
// baseline (271.502 us; speedup 1.0000x reference)
//
#include <hip/hip_runtime.h>
#include <hip/hip_bf16.h>

#define HW 65536
#define CCH 128

typedef __attribute__((ext_vector_type(8))) short short8;
typedef __attribute__((ext_vector_type(4))) float f32x4;
typedef __attribute__((ext_vector_type(8))) unsigned short u16x8;

__device__ __forceinline__ void gload_lds16(const void* g, void* l) {
    __builtin_amdgcn_global_load_lds((const __attribute__((address_space(1))) void*)g,
                                     (__attribute__((address_space(3))) void*)l, 16, 0, 0);
}
__device__ __forceinline__ unsigned short f2bf(float f) {
    union { float f; unsigned int i; } u; u.f = f;
    unsigned int r = u.i + 0x7fffu + ((u.i >> 16) & 1u);
    return (unsigned short)(r >> 16);
}
__device__ __forceinline__ float bf2f(unsigned short h) {
    union { unsigned int i; float f; } u; u.i = ((unsigned int)h) << 16; return u.f;
}
__device__ __forceinline__ unsigned int cvt_pk_bf16(float lo, float hi) {
    unsigned int r;
    asm("v_cvt_pk_bf16_f32 %0, %1, %2" : "=v"(r) : "v"(lo), "v"(hi));
    return r;
}

// ---------------- K1: adaptive avg pool 256x256 -> 8x8, f32x4 lanes ----------------
__global__ __launch_bounds__(256) void pool_kernel(const float* __restrict__ x,
                                                   float* __restrict__ pooled) {
    int bc = blockIdx.x;
    const float* base = x + (size_t)bc * HW;
    int t = threadIdx.x;
    int w = t >> 6, l = t & 63;
    for (int it = 0; it < 2; ++it) {
        int py = w + it * 4;
        const float* rp = base + py * 32 * 256 + l * 4;
        f32x4 s0 = {0.f, 0.f, 0.f, 0.f};
        f32x4 s1 = {0.f, 0.f, 0.f, 0.f};
        #pragma unroll
        for (int r = 0; r < 32; r += 2) {
            s0 += *(const f32x4*)(rp + r * 256);
            s1 += *(const f32x4*)(rp + (r + 1) * 256);
        }
        f32x4 sv = s0 + s1;
        float acc = sv[0] + sv[1] + sv[2] + sv[3];
        acc += __shfl_down(acc, 4, 8);
        acc += __shfl_down(acc, 2, 8);
        acc += __shfl_down(acc, 1, 8);
        if ((l & 7) == 0)
            pooled[(size_t)bc * 64 + py * 8 + (l >> 3)] = acc * (1.0f / 1024.0f);
    }
}

// ---------------- K2: fused q/k + A-rows + rownorm + beta; A -> bf16 hi/lo global ----------------
__global__ __launch_bounds__(256) void qkam_kernel(
        const float* __restrict__ pooled,
        const float* __restrict__ Wq, const float* __restrict__ bq,
        const float* __restrict__ Wk, const float* __restrict__ bk,
        const float* __restrict__ bv,
        unsigned short* __restrict__ Ahi, unsigned short* __restrict__ Alo,
        float* __restrict__ beta) {
    int bid = blockIdx.x;
    int bh = bid >> 2;
    int cg = bid & 3;
    int b = bh >> 3, h = bh & 7;
    int t = threadIdx.x;
    __shared__ float ps[128 * 64];
    __shared__ float Wqs[64 * 64];
    __shared__ float Wks[64 * 64];
    __shared__ float ks[128 * 68];
    __shared__ float qs[32 * 68];
    __shared__ float bvs[128];

    for (int i = t; i < 2048; i += 256) {
        int c = i >> 4, p4 = (i & 15) * 4;
        *(f32x4*)&ps[c * 64 + p4] = *(const f32x4*)(pooled + (size_t)(b * CCH + c) * 64 + p4);
    }
    for (int i = t; i < 1024; i += 256) {
        int r = i >> 4, p4 = (i & 15) * 4;
        *(f32x4*)&Wqs[r * 64 + p4] = *(const f32x4*)(Wq + (size_t)(h * 64 + r) * 64 + p4);
        *(f32x4*)&Wks[r * 64 + p4] = *(const f32x4*)(Wk + (size_t)(h * 64 + r) * 64 + p4);
    }
    if (t < 128) bvs[t] = bv[t];
    __syncthreads();

    {
        int p = t & 63, g = t >> 6;
        f32x4 wr[16];
        #pragma unroll
        for (int j = 0; j < 16; ++j) wr[j] = *(const f32x4*)&Wks[p * 64 + j * 4];
        float bkv = bk[h * 64 + p];
        for (int dd = 0; dd < 32; ++dd) {
            int d = g * 32 + dd;
            float acc = bkv;
            #pragma unroll
            for (int j = 0; j < 16; ++j) {
                f32x4 pv = *(const f32x4*)&ps[d * 64 + j * 4];
                acc += pv[0] * wr[j][0] + pv[1] * wr[j][1] + pv[2] * wr[j][2] + pv[3] * wr[j][3];
            }
            ks[d * 68 + p] = fmaxf(acc, 0.f);
        }
        #pragma unroll
        for (int j = 0; j < 16; ++j) wr[j] = *(const f32x4*)&Wqs[p * 64 + j * 4];
        float bqv = bq[h * 64 + p];
        for (int dd = 0; dd < 8; ++dd) {
            int cl = g * 8 + dd;
            int c = cg * 32 + cl;
            float acc = bqv;
            #pragma unroll
            for (int j = 0; j < 16; ++j) {
                f32x4 pv = *(const f32x4*)&ps[c * 64 + j * 4];
                acc += pv[0] * wr[j][0] + pv[1] * wr[j][1] + pv[2] * wr[j][2] + pv[3] * wr[j][3];
            }
            qs[cl * 68 + p] = fmaxf(acc, 0.f);
        }
    }
    __syncthreads();

    {
        int cl = t >> 3, dc = t & 7;
        int c = cg * 32 + cl;
        int d0 = dc * 16;
        f32x4 qr[16];
        #pragma unroll
        for (int ch = 0; ch < 16; ++ch) qr[ch] = *(const f32x4*)&qs[cl * 68 + ch * 4];
        float a[16];
        #pragma unroll
        for (int jr = 0; jr < 16; ++jr) {
            int j = (jr + dc * 2) & 15;
            int d = d0 + j;
            float acc = 0.f;
            #pragma unroll
            for (int ch = 0; ch < 16; ++ch) {
                f32x4 kr = *(const f32x4*)&ks[d * 68 + ch * 4];
                acc += qr[ch][0] * kr[0] + qr[ch][1] * kr[1] + qr[ch][2] * kr[2] + qr[ch][3] * kr[3];
            }
            a[j] = acc;
        }
        float s = 0.f;
        #pragma unroll
        for (int j = 0; j < 16; ++j) s += a[j];
        s += __shfl_xor(s, 1);
        s += __shfl_xor(s, 2);
        s += __shfl_xor(s, 4);
        float inv = 1.0f / (s + 1e-7f);
        float bpart = 0.f;
        union { unsigned short u[16]; uint4 v[2]; } ph, pl;
        #pragma unroll
        for (int j = 0; j < 16; ++j) {
            float an = a[j] * inv;
            bpart += an * bvs[d0 + j];
            unsigned short hi = f2bf(an);
            ph.u[j] = hi;
            pl.u[j] = f2bf(an - bf2f(hi));
        }
        bpart += __shfl_xor(bpart, 1);
        bpart += __shfl_xor(bpart, 2);
        bpart += __shfl_xor(bpart, 4);
        if (dc == 0) beta[bh * 128 + c] = bpart;
        size_t ao = (size_t)bh * 16384 + c * 128 + d0;
        *(uint4*)(Ahi + ao) = ph.v[0];
        *(uint4*)(Ahi + ao + 8) = ph.v[1];
        *(uint4*)(Alo + ao) = pl.v[0];
        *(uint4*)(Alo + ao + 8) = pl.v[1];
    }
}

// ---------------- K3: M = A @ Wv via MFMA; WvT hi/lo staged swizzled in LDS ----------------
__global__ __launch_bounds__(256) void am2_kernel(
        const unsigned short* __restrict__ Ahi, const unsigned short* __restrict__ Alo,
        const float* __restrict__ Wv, unsigned short* __restrict__ Mo) {
    int bid = blockIdx.x;
    int bh = bid >> 1;
    int eg = bid & 1;
    int tid = threadIdx.x;
    __shared__ __align__(16) char Wt[65536];
    for (int i = tid; i < 4096; i += 256) {
        int d = i >> 5, e4 = (i & 31) * 4;
        f32x4 v = *(const f32x4*)(Wv + (size_t)d * 128 + e4);
        #pragma unroll
        for (int j = 0; j < 4; ++j) {
            int e = e4 + j;
            unsigned short hi = f2bf(v[j]);
            unsigned short lo = f2bf(v[j] - bf2f(hi));
            int o = (e * 256 + d * 2) ^ ((e & 7) << 4);
            *(unsigned short*)(Wt + o) = hi;
            *(unsigned short*)(Wt + 32768 + o) = lo;
        }
    }
    __syncthreads();
    int w = tid >> 6, l = tid & 63;
    int lc = l & 15, lk = (l >> 4) * 8;
    f32x4 acc[2][4] = {};
    const unsigned short* Ab = Ahi + (size_t)bh * 16384;
    const unsigned short* Alb = Alo + (size_t)bh * 16384;
    #pragma unroll
    for (int ksi = 0; ksi < 4; ++ksi) {
        int d = ksi * 32 + lk;
        short8 ah[2], al[2], bhv[4], blv[4];
        #pragma unroll
        for (int ci = 0; ci < 2; ++ci) {
            int c = w * 32 + ci * 16 + lc;
            ah[ci] = *(const short8*)(Ab + c * 128 + d);
            al[ci] = *(const short8*)(Alb + c * 128 + d);
        }
        #pragma unroll
        for (int ei = 0; ei < 4; ++ei) {
            int e = eg * 64 + ei * 16 + lc;
            int o = (e * 256 + d * 2) ^ ((e & 7) << 4);
            bhv[ei] = *(const short8*)(Wt + o);
            blv[ei] = *(const short8*)(Wt + 32768 + o);
        }
        #pragma unroll
        for (int ci = 0; ci < 2; ++ci)
            #pragma unroll
            for (int ei = 0; ei < 4; ++ei) {
                acc[ci][ei] = __builtin_amdgcn_mfma_f32_16x16x32_bf16(ah[ci], bhv[ei], acc[ci][ei], 0, 0, 0);
                acc[ci][ei] = __builtin_amdgcn_mfma_f32_16x16x32_bf16(ah[ci], blv[ei], acc[ci][ei], 0, 0, 0);
                acc[ci][ei] = __builtin_amdgcn_mfma_f32_16x16x32_bf16(al[ci], bhv[ei], acc[ci][ei], 0, 0, 0);
            }
    }
    unsigned short* Mb = Mo + (size_t)bh * 16384;
    #pragma unroll
    for (int ci = 0; ci < 2; ++ci)
        #pragma unroll
        for (int ei = 0; ei < 4; ++ei)
            #pragma unroll
            for (int r = 0; r < 4; ++r) {
                int c = w * 32 + ci * 16 + (l >> 4) * 4 + r;
                int e = eg * 64 + ei * 16 + lc;
                Mb[c * 128 + e] = f2bf(acc[ci][ei][r]);
            }
}

// ---------------- K4: attn[c][s] = sum_e M[c][e]*x[e][s] + beta[c], bf16 MFMA ----------------
// Round-9 config (best measured): 80 KB LDS, 1024 blocks = 2 even rounds at 2 blocks/CU,
// LDS outstage epilogue (no write amplification), 16-position swizzle.
__global__ __launch_bounds__(512, 4) void attn_kernel(
        const float* __restrict__ x,
        const __hip_bfloat16* __restrict__ Mbf,
        const float* __restrict__ beta,
        __hip_bfloat16* __restrict__ attn) {
    int bid = blockIdx.x;
    int bh = bid >> 4;
    int chunk = bid & 15;
    int b = bh >> 3, h = bh & 7;
    int s0g = h * 8192 + chunk * 512;
    int tid = threadIdx.x;
    int w = tid >> 6, l = tid & 63;

    __shared__ __align__(16) char sm[81920];
    char* ts0 = sm + 32768;
    char* ost = sm + 65536;

    const char* Mg = (const char*)(Mbf + (size_t)bh * 16384);
    #pragma unroll
    for (int i = 0; i < 4; ++i) {
        int o = i * 8192 + tid * 16;
        int osw = o ^ (((o >> 8) & 15) << 4);
        gload_lds16(Mg + osw, sm + o);
    }

    int e0u = (tid >> 4) * 2;
    int s4u = (tid & 15) * 4;
    const float* xb = x + (size_t)b * CCH * HW + s0g;

    f32x4 rg[4];
    #define LOADT(t_) do { \
        const float* p0 = xb + (size_t)e0u * HW + (t_) * 64 + s4u; \
        rg[0] = *(const f32x4*)p0; \
        rg[1] = *(const f32x4*)(p0 + HW); \
        const float* p1 = p0 + (size_t)64 * HW; \
        rg[2] = *(const f32x4*)p1; \
        rg[3] = *(const f32x4*)(p1 + HW); \
    } while (0)
    #define WRITET(buf_) do { \
        _Pragma("unroll") \
        for (int j = 0; j < 4; ++j) { \
            int s = s4u + j; \
            int sw = (s & 15) << 4; \
            unsigned int pa = cvt_pk_bf16(rg[0][j], rg[1][j]); \
            unsigned int pb = cvt_pk_bf16(rg[2][j], rg[3][j]); \
            *(unsigned int*)((buf_) + ((s * 256 + e0u * 2) ^ sw)) = pa; \
            *(unsigned int*)((buf_) + ((s * 256 + (e0u + 64) * 2) ^ sw)) = pb; \
        } \
    } while (0)

    LOADT(0);
    WRITET(ts0);
    LOADT(1);
    __syncthreads();   // M + tile0 staged

    int c0w = (w >> 1) * 32;
    int s0w = (w & 1) * 32;
    short8 mf[2][4];
    #pragma unroll
    for (int ci = 0; ci < 2; ++ci)
        #pragma unroll
        for (int ksi = 0; ksi < 4; ++ksi) {
            int c = c0w + ci * 16 + (l & 15);
            int o = (c * 256 + ksi * 64 + ((l >> 4) * 16)) ^ ((c & 15) << 4);
            mf[ci][ksi] = *(const short8*)(sm + o);
        }
    const float* bet = beta + bh * 128;
    float bv0 = bet[c0w + (l & 15)];
    float bv1 = bet[c0w + 16 + (l & 15)];
    __hip_bfloat16* ab = attn + (size_t)b * CCH * HW + s0g;

    for (int t = 0; t < 8; ++t) {
        char* tsc = ts0 + (t & 1) * 16384;
        if (t < 7) WRITET(ts0 + ((t + 1) & 1) * 16384);   // rg holds tile t+1
        if (t < 6) LOADT(t + 2);
        f32x4 acc[2][2] = {};
        #pragma unroll
        for (int ksi = 0; ksi < 4; ++ksi) {
            short8 af[2];
            #pragma unroll
            for (int si = 0; si < 2; ++si) {
                int s = s0w + si * 16 + (l & 15);
                int o = (s * 256 + ksi * 64 + ((l >> 4) * 16)) ^ ((s & 15) << 4);
                af[si] = *(const short8*)(tsc + o);
            }
            #pragma unroll
            for (int si = 0; si < 2; ++si)
                #pragma unroll
                for (int ci = 0; ci < 2; ++ci)
                    acc[si][ci] = __builtin_amdgcn_mfma_f32_16x16x32_bf16(af[si], mf[ci][ksi], acc[si][ci], 0, 0, 0);
        }
        // pack accumulators into outstage ob[c][s] (swizzled)
        #pragma unroll
        for (int si = 0; si < 2; ++si)
            #pragma unroll
            for (int ci = 0; ci < 2; ++ci) {
                int sb = s0w + si * 16 + (l >> 4) * 4;
                int c = c0w + ci * 16 + (l & 15);
                float bvv = ci ? bv1 : bv0;
                uint2 pk2;
                pk2.x = cvt_pk_bf16(acc[si][ci][0] + bvv, acc[si][ci][1] + bvv);
                pk2.y = cvt_pk_bf16(acc[si][ci][2] + bvv, acc[si][ci][3] + bvv);
                int o = (c * 128 + sb * 2) ^ ((c & 7) << 4);
                *(uint2*)(ost + o) = pk2;
            }
        __syncthreads();   // B1: pack done; tsc reads done; tile t+1 written
        // coalesced stores: each c-row = 128 B written by 8 lanes (full line)
        #pragma unroll
        for (int p = 0; p < 2; ++p) {
            int c = p * 64 + (tid >> 3);
            int kk = tid & 7;
            int o = (c * 128 + kk * 16) ^ ((c & 7) << 4);
            *(int4*)((char*)(ab + (size_t)c * HW + t * 64) + kk * 16) = *(const int4*)(ost + o);
        }
        __syncthreads();   // B2: outstage reads done before next iter's pack
    }
    #undef LOADT
    #undef WRITET
}

// ---------------- K5: depthwise 3x3 pad1 + bp, registers + shfl halos, no LDS ----------------
__global__ __launch_bounds__(256) void dwconv_kernel(const __hip_bfloat16* __restrict__ attn,
        const float* __restrict__ Wp, const float* __restrict__ bp,
        float* __restrict__ out) {
    int bid = blockIdx.x;
    int bc = bid >> 5;
    int y0 = (bid & 31) * 8;
    int t = threadIdx.x;
    int l = t & 63;
    int y = y0 + ((t >> 6) << 1) + (l >> 5);   // wave = 2 full image rows
    int xl = l & 31;
    int xc = xl * 8;
    const unsigned short* base = (const unsigned short*)attn + (size_t)bc * HW;
    int c = bc & 127;
    float wv[9];
    #pragma unroll
    for (int j = 0; j < 9; ++j) wv[j] = Wp[c * 9 + j];
    float bias = bp[c];
    float accv[8];
    #pragma unroll
    for (int j = 0; j < 8; ++j) accv[j] = bias;
    #pragma unroll
    for (int dy = 0; dy < 3; ++dy) {
        int gy = y + dy - 1;
        u16x8 m = (u16x8)((unsigned short)0);
        if (gy >= 0 && gy < 256) m = *(const u16x8*)(base + gy * 256 + xc);
        float f[8];
        #pragma unroll
        for (int j = 0; j < 8; ++j) f[j] = bf2f(m[j]);
        float lf = __shfl(f[7], l - 1);
        float rf = __shfl(f[0], l + 1);
        if (xl == 0) lf = 0.f;
        if (xl == 31) rf = 0.f;
        float w0 = wv[dy * 3], w1 = wv[dy * 3 + 1], w2 = wv[dy * 3 + 2];
        accv[0] += w0 * lf + w1 * f[0] + w2 * f[1];
        #pragma unroll
        for (int j = 1; j < 7; ++j)
            accv[j] += w0 * f[j - 1] + w1 * f[j] + w2 * f[j + 1];
        accv[7] += w0 * f[6] + w1 * f[7] + w2 * rf;
    }
    float* op = out + (size_t)bc * HW + (size_t)y * 256 + xc;
    float4 o0 = {accv[0], accv[1], accv[2], accv[3]};
    float4 o1 = {accv[4], accv[5], accv[6], accv[7]};
    *(float4*)op = o0;
    *(float4*)(op + 4) = o1;
}

extern "C" void kernel_launch(void* const* d_in, const int* in_sizes, int n_in,
                              void* d_out, int out_size, void* d_ws, size_t ws_size,
                              hipStream_t stream) {
    const float* x  = (const float*)d_in[0];
    const float* Wq = (const float*)d_in[1];
    const float* bq = (const float*)d_in[2];
    const float* Wk = (const float*)d_in[3];
    const float* bk = (const float*)d_in[4];
    const float* Wv = (const float*)d_in[5];
    const float* bv = (const float*)d_in[6];
    const float* Wp = (const float*)d_in[7];
    const float* bp = (const float*)d_in[8];
    float* out = (float*)d_out;
    char* ws = (char*)d_ws;

    float* pooled      = (float*)ws;                            // 256 KB
    unsigned short* Ahi = (unsigned short*)(ws + 262144);       // 2 MB
    unsigned short* Alo = (unsigned short*)(ws + 2359296);      // 2 MB
    unsigned short* Mo  = (unsigned short*)(ws + 4456448);      // 2 MB
    float* betab       = (float*)(ws + 6553600);                // 32 KB
    char* attnp        = ws + 6586368;                          // 128 MB

    pool_kernel<<<dim3(1024), dim3(256), 0, stream>>>(x, pooled);
    qkam_kernel<<<dim3(256), dim3(256), 0, stream>>>(pooled, Wq, bq, Wk, bk, bv, Ahi, Alo, betab);
    am2_kernel<<<dim3(128), dim3(256), 0, stream>>>(Ahi, Alo, Wv, Mo);
    attn_kernel<<<dim3(1024), dim3(512), 0, stream>>>(x, (const __hip_bfloat16*)Mo, betab, (__hip_bfloat16*)attnp);
    dwconv_kernel<<<dim3(32768), dim3(256), 0, stream>>>((const __hip_bfloat16*)attnp, Wp, bp, out);
}

// Round 14
// 264.599 us; speedup vs baseline: 1.0261x; 1.0261x over previous
//
#include <hip/hip_runtime.h>
#include <hip/hip_bf16.h>

#define HW 65536
#define CCH 128

typedef __attribute__((ext_vector_type(8))) short short8;
typedef __attribute__((ext_vector_type(4))) float f32x4;
typedef __attribute__((ext_vector_type(8))) unsigned short u16x8;

__device__ __forceinline__ void gload_lds16(const void* g, void* l) {
    __builtin_amdgcn_global_load_lds((const __attribute__((address_space(1))) void*)g,
                                     (__attribute__((address_space(3))) void*)l, 16, 0, 0);
}
__device__ __forceinline__ unsigned short f2bf(float f) {
    union { float f; unsigned int i; } u; u.f = f;
    unsigned int r = u.i + 0x7fffu + ((u.i >> 16) & 1u);
    return (unsigned short)(r >> 16);
}
__device__ __forceinline__ float bf2f(unsigned short h) {
    union { unsigned int i; float f; } u; u.i = ((unsigned int)h) << 16; return u.f;
}
__device__ __forceinline__ unsigned int cvt_pk_bf16(float lo, float hi) {
    unsigned int r;
    asm("v_cvt_pk_bf16_f32 %0, %1, %2" : "=v"(r) : "v"(lo), "v"(hi));
    return r;
}

// ---------------- K1: adaptive avg pool 256x256 -> 8x8, f32x4 lanes ----------------
__global__ __launch_bounds__(256) void pool_kernel(const float* __restrict__ x,
                                                   float* __restrict__ pooled) {
    int bc = blockIdx.x;
    const float* base = x + (size_t)bc * HW;
    int t = threadIdx.x;
    int w = t >> 6, l = t & 63;
    for (int it = 0; it < 2; ++it) {
        int py = w + it * 4;
        const float* rp = base + py * 32 * 256 + l * 4;
        f32x4 s0 = {0.f, 0.f, 0.f, 0.f};
        f32x4 s1 = {0.f, 0.f, 0.f, 0.f};
        #pragma unroll
        for (int r = 0; r < 32; r += 2) {
            s0 += *(const f32x4*)(rp + r * 256);
            s1 += *(const f32x4*)(rp + (r + 1) * 256);
        }
        f32x4 sv = s0 + s1;
        float acc = sv[0] + sv[1] + sv[2] + sv[3];
        acc += __shfl_down(acc, 4, 8);
        acc += __shfl_down(acc, 2, 8);
        acc += __shfl_down(acc, 1, 8);
        if ((l & 7) == 0)
            pooled[(size_t)bc * 64 + py * 8 + (l >> 3)] = acc * (1.0f / 1024.0f);
    }
}

// ---------------- K2: fused q/k + A-rows + rownorm + beta; A -> bf16 hi/lo global ----------------
__global__ __launch_bounds__(256) void qkam_kernel(
        const float* __restrict__ pooled,
        const float* __restrict__ Wq, const float* __restrict__ bq,
        const float* __restrict__ Wk, const float* __restrict__ bk,
        const float* __restrict__ bv,
        unsigned short* __restrict__ Ahi, unsigned short* __restrict__ Alo,
        float* __restrict__ beta) {
    int bid = blockIdx.x;
    int bh = bid >> 2;
    int cg = bid & 3;
    int b = bh >> 3, h = bh & 7;
    int t = threadIdx.x;
    __shared__ float ps[128 * 64];
    __shared__ float Wqs[64 * 64];
    __shared__ float Wks[64 * 64];
    __shared__ float ks[128 * 68];
    __shared__ float qs[32 * 68];
    __shared__ float bvs[128];

    for (int i = t; i < 2048; i += 256) {
        int c = i >> 4, p4 = (i & 15) * 4;
        *(f32x4*)&ps[c * 64 + p4] = *(const f32x4*)(pooled + (size_t)(b * CCH + c) * 64 + p4);
    }
    for (int i = t; i < 1024; i += 256) {
        int r = i >> 4, p4 = (i & 15) * 4;
        *(f32x4*)&Wqs[r * 64 + p4] = *(const f32x4*)(Wq + (size_t)(h * 64 + r) * 64 + p4);
        *(f32x4*)&Wks[r * 64 + p4] = *(const f32x4*)(Wk + (size_t)(h * 64 + r) * 64 + p4);
    }
    if (t < 128) bvs[t] = bv[t];
    __syncthreads();

    {
        int p = t & 63, g = t >> 6;
        f32x4 wr[16];
        #pragma unroll
        for (int j = 0; j < 16; ++j) wr[j] = *(const f32x4*)&Wks[p * 64 + j * 4];
        float bkv = bk[h * 64 + p];
        for (int dd = 0; dd < 32; ++dd) {
            int d = g * 32 + dd;
            float acc = bkv;
            #pragma unroll
            for (int j = 0; j < 16; ++j) {
                f32x4 pv = *(const f32x4*)&ps[d * 64 + j * 4];
                acc += pv[0] * wr[j][0] + pv[1] * wr[j][1] + pv[2] * wr[j][2] + pv[3] * wr[j][3];
            }
            ks[d * 68 + p] = fmaxf(acc, 0.f);
        }
        #pragma unroll
        for (int j = 0; j < 16; ++j) wr[j] = *(const f32x4*)&Wqs[p * 64 + j * 4];
        float bqv = bq[h * 64 + p];
        for (int dd = 0; dd < 8; ++dd) {
            int cl = g * 8 + dd;
            int c = cg * 32 + cl;
            float acc = bqv;
            #pragma unroll
            for (int j = 0; j < 16; ++j) {
                f32x4 pv = *(const f32x4*)&ps[c * 64 + j * 4];
                acc += pv[0] * wr[j][0] + pv[1] * wr[j][1] + pv[2] * wr[j][2] + pv[3] * wr[j][3];
            }
            qs[cl * 68 + p] = fmaxf(acc, 0.f);
        }
    }
    __syncthreads();

    {
        int cl = t >> 3, dc = t & 7;
        int c = cg * 32 + cl;
        int d0 = dc * 16;
        f32x4 qr[16];
        #pragma unroll
        for (int ch = 0; ch < 16; ++ch) qr[ch] = *(const f32x4*)&qs[cl * 68 + ch * 4];
        float a[16];
        #pragma unroll
        for (int jr = 0; jr < 16; ++jr) {
            int j = (jr + dc * 2) & 15;
            int d = d0 + j;
            float acc = 0.f;
            #pragma unroll
            for (int ch = 0; ch < 16; ++ch) {
                f32x4 kr = *(const f32x4*)&ks[d * 68 + ch * 4];
                acc += qr[ch][0] * kr[0] + qr[ch][1] * kr[1] + qr[ch][2] * kr[2] + qr[ch][3] * kr[3];
            }
            a[j] = acc;
        }
        float s = 0.f;
        #pragma unroll
        for (int j = 0; j < 16; ++j) s += a[j];
        s += __shfl_xor(s, 1);
        s += __shfl_xor(s, 2);
        s += __shfl_xor(s, 4);
        float inv = 1.0f / (s + 1e-7f);
        float bpart = 0.f;
        union { unsigned short u[16]; uint4 v[2]; } ph, pl;
        #pragma unroll
        for (int j = 0; j < 16; ++j) {
            float an = a[j] * inv;
            bpart += an * bvs[d0 + j];
            unsigned short hi = f2bf(an);
            ph.u[j] = hi;
            pl.u[j] = f2bf(an - bf2f(hi));
        }
        bpart += __shfl_xor(bpart, 1);
        bpart += __shfl_xor(bpart, 2);
        bpart += __shfl_xor(bpart, 4);
        if (dc == 0) beta[bh * 128 + c] = bpart;
        size_t ao = (size_t)bh * 16384 + c * 128 + d0;
        *(uint4*)(Ahi + ao) = ph.v[0];
        *(uint4*)(Ahi + ao + 8) = ph.v[1];
        *(uint4*)(Alo + ao) = pl.v[0];
        *(uint4*)(Alo + ao + 8) = pl.v[1];
    }
}

// ---------------- K3: M = A @ Wv via MFMA; WvT hi/lo staged swizzled in LDS ----------------
__global__ __launch_bounds__(256) void am2_kernel(
        const unsigned short* __restrict__ Ahi, const unsigned short* __restrict__ Alo,
        const float* __restrict__ Wv, unsigned short* __restrict__ Mo) {
    int bid = blockIdx.x;
    int bh = bid >> 1;
    int eg = bid & 1;
    int tid = threadIdx.x;
    __shared__ __align__(16) char Wt[65536];
    for (int i = tid; i < 4096; i += 256) {
        int d = i >> 5, e4 = (i & 31) * 4;
        f32x4 v = *(const f32x4*)(Wv + (size_t)d * 128 + e4);
        #pragma unroll
        for (int j = 0; j < 4; ++j) {
            int e = e4 + j;
            unsigned short hi = f2bf(v[j]);
            unsigned short lo = f2bf(v[j] - bf2f(hi));
            int o = (e * 256 + d * 2) ^ ((e & 7) << 4);
            *(unsigned short*)(Wt + o) = hi;
            *(unsigned short*)(Wt + 32768 + o) = lo;
        }
    }
    __syncthreads();
    int w = tid >> 6, l = tid & 63;
    int lc = l & 15, lk = (l >> 4) * 8;
    f32x4 acc[2][4] = {};
    const unsigned short* Ab = Ahi + (size_t)bh * 16384;
    const unsigned short* Alb = Alo + (size_t)bh * 16384;
    #pragma unroll
    for (int ksi = 0; ksi < 4; ++ksi) {
        int d = ksi * 32 + lk;
        short8 ah[2], al[2], bhv[4], blv[4];
        #pragma unroll
        for (int ci = 0; ci < 2; ++ci) {
            int c = w * 32 + ci * 16 + lc;
            ah[ci] = *(const short8*)(Ab + c * 128 + d);
            al[ci] = *(const short8*)(Alb + c * 128 + d);
        }
        #pragma unroll
        for (int ei = 0; ei < 4; ++ei) {
            int e = eg * 64 + ei * 16 + lc;
            int o = (e * 256 + d * 2) ^ ((e & 7) << 4);
            bhv[ei] = *(const short8*)(Wt + o);
            blv[ei] = *(const short8*)(Wt + 32768 + o);
        }
        #pragma unroll
        for (int ci = 0; ci < 2; ++ci)
            #pragma unroll
            for (int ei = 0; ei < 4; ++ei) {
                acc[ci][ei] = __builtin_amdgcn_mfma_f32_16x16x32_bf16(ah[ci], bhv[ei], acc[ci][ei], 0, 0, 0);
                acc[ci][ei] = __builtin_amdgcn_mfma_f32_16x16x32_bf16(ah[ci], blv[ei], acc[ci][ei], 0, 0, 0);
                acc[ci][ei] = __builtin_amdgcn_mfma_f32_16x16x32_bf16(al[ci], bhv[ei], acc[ci][ei], 0, 0, 0);
            }
    }
    unsigned short* Mb = Mo + (size_t)bh * 16384;
    #pragma unroll
    for (int ci = 0; ci < 2; ++ci)
        #pragma unroll
        for (int ei = 0; ei < 4; ++ei)
            #pragma unroll
            for (int r = 0; r < 4; ++r) {
                int c = w * 32 + ci * 16 + (l >> 4) * 4 + r;
                int e = eg * 64 + ei * 16 + lc;
                Mb[c * 128 + e] = f2bf(acc[ci][ei][r]);
            }
}

// ---------------- K4: attn[c][s] = sum_e M[c][e]*x[e][s] + beta[c], bf16 MFMA ----------------
// Best-measured config (R9): 80 KB LDS, 1024 blocks = 2 even rounds at 2 blocks/CU,
// LDS outstage epilogue (no write amplification), 16-position swizzle.
__global__ __launch_bounds__(512, 4) void attn_kernel(
        const float* __restrict__ x,
        const __hip_bfloat16* __restrict__ Mbf,
        const float* __restrict__ beta,
        __hip_bfloat16* __restrict__ attn) {
    int bid = blockIdx.x;
    int bh = bid >> 4;
    int chunk = bid & 15;
    int b = bh >> 3, h = bh & 7;
    int s0g = h * 8192 + chunk * 512;
    int tid = threadIdx.x;
    int w = tid >> 6, l = tid & 63;

    __shared__ __align__(16) char sm[81920];
    char* ts0 = sm + 32768;
    char* ost = sm + 65536;

    const char* Mg = (const char*)(Mbf + (size_t)bh * 16384);
    #pragma unroll
    for (int i = 0; i < 4; ++i) {
        int o = i * 8192 + tid * 16;
        int osw = o ^ (((o >> 8) & 15) << 4);
        gload_lds16(Mg + osw, sm + o);
    }

    int e0u = (tid >> 4) * 2;
    int s4u = (tid & 15) * 4;
    const float* xb = x + (size_t)b * CCH * HW + s0g;

    f32x4 rg[4];
    #define LOADT(t_) do { \
        const float* p0 = xb + (size_t)e0u * HW + (t_) * 64 + s4u; \
        rg[0] = *(const f32x4*)p0; \
        rg[1] = *(const f32x4*)(p0 + HW); \
        const float* p1 = p0 + (size_t)64 * HW; \
        rg[2] = *(const f32x4*)p1; \
        rg[3] = *(const f32x4*)(p1 + HW); \
    } while (0)
    #define WRITET(buf_) do { \
        _Pragma("unroll") \
        for (int j = 0; j < 4; ++j) { \
            int s = s4u + j; \
            int sw = (s & 15) << 4; \
            unsigned int pa = cvt_pk_bf16(rg[0][j], rg[1][j]); \
            unsigned int pb = cvt_pk_bf16(rg[2][j], rg[3][j]); \
            *(unsigned int*)((buf_) + ((s * 256 + e0u * 2) ^ sw)) = pa; \
            *(unsigned int*)((buf_) + ((s * 256 + (e0u + 64) * 2) ^ sw)) = pb; \
        } \
    } while (0)

    LOADT(0);
    WRITET(ts0);
    LOADT(1);
    __syncthreads();   // M + tile0 staged

    int c0w = (w >> 1) * 32;
    int s0w = (w & 1) * 32;
    short8 mf[2][4];
    #pragma unroll
    for (int ci = 0; ci < 2; ++ci)
        #pragma unroll
        for (int ksi = 0; ksi < 4; ++ksi) {
            int c = c0w + ci * 16 + (l & 15);
            int o = (c * 256 + ksi * 64 + ((l >> 4) * 16)) ^ ((c & 15) << 4);
            mf[ci][ksi] = *(const short8*)(sm + o);
        }
    const float* bet = beta + bh * 128;
    float bv0 = bet[c0w + (l & 15)];
    float bv1 = bet[c0w + 16 + (l & 15)];
    __hip_bfloat16* ab = attn + (size_t)b * CCH * HW + s0g;

    for (int t = 0; t < 8; ++t) {
        char* tsc = ts0 + (t & 1) * 16384;
        if (t < 7) WRITET(ts0 + ((t + 1) & 1) * 16384);   // rg holds tile t+1
        if (t < 6) LOADT(t + 2);
        f32x4 acc[2][2] = {};
        #pragma unroll
        for (int ksi = 0; ksi < 4; ++ksi) {
            short8 af[2];
            #pragma unroll
            for (int si = 0; si < 2; ++si) {
                int s = s0w + si * 16 + (l & 15);
                int o = (s * 256 + ksi * 64 + ((l >> 4) * 16)) ^ ((s & 15) << 4);
                af[si] = *(const short8*)(tsc + o);
            }
            #pragma unroll
            for (int si = 0; si < 2; ++si)
                #pragma unroll
                for (int ci = 0; ci < 2; ++ci)
                    acc[si][ci] = __builtin_amdgcn_mfma_f32_16x16x32_bf16(af[si], mf[ci][ksi], acc[si][ci], 0, 0, 0);
        }
        // pack accumulators into outstage ob[c][s] (swizzled)
        #pragma unroll
        for (int si = 0; si < 2; ++si)
            #pragma unroll
            for (int ci = 0; ci < 2; ++ci) {
                int sb = s0w + si * 16 + (l >> 4) * 4;
                int c = c0w + ci * 16 + (l & 15);
                float bvv = ci ? bv1 : bv0;
                uint2 pk2;
                pk2.x = cvt_pk_bf16(acc[si][ci][0] + bvv, acc[si][ci][1] + bvv);
                pk2.y = cvt_pk_bf16(acc[si][ci][2] + bvv, acc[si][ci][3] + bvv);
                int o = (c * 128 + sb * 2) ^ ((c & 7) << 4);
                *(uint2*)(ost + o) = pk2;
            }
        __syncthreads();   // B1: pack done; tsc reads done; tile t+1 written
        // coalesced stores: each c-row = 128 B written by 8 lanes (full line)
        #pragma unroll
        for (int p = 0; p < 2; ++p) {
            int c = p * 64 + (tid >> 3);
            int kk = tid & 7;
            int o = (c * 128 + kk * 16) ^ ((c & 7) << 4);
            *(int4*)((char*)(ab + (size_t)c * HW + t * 64) + kk * 16) = *(const int4*)(ost + o);
        }
        __syncthreads();   // B2: outstage reads done before next iter's pack
    }
    #undef LOADT
    #undef WRITET
}

// ---------------- K5: depthwise 3x3 pad1 + bp, bf16 in -> fp32 out (bf16 LDS tile) ----------------
__global__ __launch_bounds__(256) void dwconv_kernel(const __hip_bfloat16* __restrict__ attn,
        const float* __restrict__ Wp, const float* __restrict__ bp,
        float* __restrict__ out) {
    int bid = blockIdx.x;
    int bc = bid >> 3;
    int ys = bid & 7;
    int y0 = ys * 32;
    int t = threadIdx.x;
    __shared__ unsigned short tile[34][264];
    const unsigned short* base = (const unsigned short*)attn + (size_t)bc * HW;
    for (int i = t; i < 34 * 32; i += 256) {
        int r = i >> 5, ck = i & 31;
        int gy = y0 + r - 1;
        u16x8 v;
        if (gy >= 0 && gy < 256) v = *(const u16x8*)(base + gy * 256 + ck * 8);
        else v = (u16x8)((unsigned short)0);
        *(u16x8*)&tile[r][ck * 8] = v;
    }
    __syncthreads();
    int c = bc & 127;
    float wv[9];
    #pragma unroll
    for (int j = 0; j < 9; ++j) wv[j] = Wp[c * 9 + j];
    float bias = bp[c];
    float* obase = out + (size_t)bc * HW;
    for (int p = 0; p < 4; ++p) {
        int orow = p * 8 + (t >> 5);
        int oc = (t & 31) * 8;
        float accv[8];
        #pragma unroll
        for (int j = 0; j < 8; ++j) accv[j] = bias;
        #pragma unroll
        for (int dy = 0; dy < 3; ++dy) {
            int tr = orow + dy;
            u16x8 m = *(const u16x8*)&tile[tr][oc];
            float f[10];
            f[0] = (oc == 0) ? 0.f : bf2f(tile[tr][oc - 1]);
            #pragma unroll
            for (int j = 0; j < 8; ++j) f[j + 1] = bf2f(m[j]);
            f[9] = (oc == 248) ? 0.f : bf2f(tile[tr][oc + 8]);
            float w0 = wv[dy * 3], w1 = wv[dy * 3 + 1], w2 = wv[dy * 3 + 2];
            #pragma unroll
            for (int j = 0; j < 8; ++j)
                accv[j] += w0 * f[j] + w1 * f[j + 1] + w2 * f[j + 2];
        }
        float* op = obase + (size_t)(y0 + orow) * 256 + oc;
        float4 o0 = {accv[0], accv[1], accv[2], accv[3]};
        float4 o1 = {accv[4], accv[5], accv[6], accv[7]};
        *(float4*)op = o0;
        *(float4*)(op + 4) = o1;
    }
}

extern "C" void kernel_launch(void* const* d_in, const int* in_sizes, int n_in,
                              void* d_out, int out_size, void* d_ws, size_t ws_size,
                              hipStream_t stream) {
    const float* x  = (const float*)d_in[0];
    const float* Wq = (const float*)d_in[1];
    const float* bq = (const float*)d_in[2];
    const float* Wk = (const float*)d_in[3];
    const float* bk = (const float*)d_in[4];
    const float* Wv = (const float*)d_in[5];
    const float* bv = (const float*)d_in[6];
    const float* Wp = (const float*)d_in[7];
    const float* bp = (const float*)d_in[8];
    float* out = (float*)d_out;
    char* ws = (char*)d_ws;

    float* pooled      = (float*)ws;                            // 256 KB
    unsigned short* Ahi = (unsigned short*)(ws + 262144);       // 2 MB
    unsigned short* Alo = (unsigned short*)(ws + 2359296);      // 2 MB
    unsigned short* Mo  = (unsigned short*)(ws + 4456448);      // 2 MB
    float* betab       = (float*)(ws + 6553600);                // 32 KB
    char* attnp        = ws + 6586368;                          // 128 MB

    pool_kernel<<<dim3(1024), dim3(256), 0, stream>>>(x, pooled);
    qkam_kernel<<<dim3(256), dim3(256), 0, stream>>>(pooled, Wq, bq, Wk, bk, bv, Ahi, Alo, betab);
    am2_kernel<<<dim3(128), dim3(256), 0, stream>>>(Ahi, Alo, Wv, Mo);
    attn_kernel<<<dim3(1024), dim3(512), 0, stream>>>(x, (const __hip_bfloat16*)Mo, betab, (__hip_bfloat16*)attnp);
    dwconv_kernel<<<dim3(8192), dim3(256), 0, stream>>>((const __hip_bfloat16*)attnp, Wp, bp, out);
}